// Round 1
// baseline (958.476 us; speedup 1.0000x reference)
//
#include <hip/hip_runtime.h>
#include <hip/hip_bf16.h>
#include <stdint.h>

// Problem constants
#define B_   64
#define S_   200
#define H_   128
#define V_   20000
#define M_   12800      // B_*S_
#define NPAD 20096      // 157*128
#define NBN  157
#define NBM  100

// ws offsets (bytes) — total ~17.04 MB, all read during final GEMM pass
#define WS_A      0u          // A_bf16 [12800][256]  6,553,600 B
#define WS_FCW    6554112u    // fcW_bf16 [20096][256] 10,289,152 B
#define WS_FCB    16843264u   // fc_b padded [20096] f32
#define WS_RSUM   16923648u   // rowsum [12800] f32
#define WS_WTIH   16974848u   // W_ih^T [128][128] f32
// end 17,040,384

// scratch inside the y region of d_out (float offsets) — overwritten by final pass
#define XP_OFF    0
#define HOUT_OFF  2000000
#define PART_OFF  4000000          // [NBN][12800] partial exp-sums
#define OUTPU_OFF 256000000ll      // real output 1 (out_pu) lives here

typedef __attribute__((ext_vector_type(8))) __bf16 bf16x8;
typedef __attribute__((ext_vector_type(4))) float  f32x4;

__device__ __forceinline__ void gll16(const void* g, void* l) {
  __builtin_amdgcn_global_load_lds(
      (const __attribute__((address_space(1))) void*)g,
      (__attribute__((address_space(3))) void*)l, 16, 0, 0);
}

// ---------------- prep kernels ----------------
__global__ void prep_fcw(const float* __restrict__ fcw, __hip_bfloat16* __restrict__ out) {
  int n = blockIdx.x, k = threadIdx.x;               // grid 20096 x 256
  float v = (n < V_) ? fcw[(long)n * 256 + k] : 0.f;
  out[(long)n * 256 + k] = __float2bfloat16(v);
}

__global__ void prep_small(const float* __restrict__ w_ih, const float* __restrict__ fcb,
                           float* __restrict__ wt, float* __restrict__ fcbp) {
  int bid = blockIdx.x, t = threadIdx.x;             // grid 207 x 256
  if (bid < 128) {
    if (t < 128) wt[bid * 128 + t] = w_ih[t * 128 + bid];   // wt[k][j] = W_ih[j][k]
  } else {
    int idx = (bid - 128) * 256 + t;
    if (idx < NPAD) fcbp[idx] = (idx < V_) ? fcb[idx] : -1e30f;
  }
}

// ---------------- K1: x_proj = emb[poi] @ W_ih^T + b_ih + b_hh ----------------
__global__ __launch_bounds__(128)
void xproj_k(const int* __restrict__ poi, const float* __restrict__ emb,
             const float* __restrict__ wt_ih, const float* __restrict__ b_ih,
             const float* __restrict__ b_hh, float* __restrict__ xp) {
  __shared__ float xs[128];
  int m = blockIdx.x, j = threadIdx.x;               // grid 12800 x 128
  xs[j] = emb[(long)poi[m] * 128 + j];
  __syncthreads();
  float acc = b_ih[j] + b_hh[j];
#pragma unroll 8
  for (int k = 0; k < 128; ++k) acc = fmaf(xs[k], wt_ih[k * 128 + j], acc);
  xp[(long)m * 128 + j] = acc;
}

// ---------------- K2: sequential RNN (one block per batch row) ----------------
__global__ __launch_bounds__(128)
void rnn_k(const float* __restrict__ xp, const float* __restrict__ w_hh,
           float* __restrict__ hout) {
  int b = blockIdx.x, j = threadIdx.x;               // grid 64 x 128
  float w[128];
#pragma unroll
  for (int k = 0; k < 128; ++k) w[k] = w_hh[j * 128 + k];   // W_hh row j in regs
  __shared__ float hs[2][128];
  hs[0][j] = 0.f;
  __syncthreads();
  int cur = 0;
  for (int t = 0; t < S_; ++t) {
    float acc = xp[((long)b * S_ + t) * 128 + j];
    const float* hp = hs[cur];
#pragma unroll
    for (int k = 0; k < 128; ++k) acc = fmaf(hp[k], w[k], acc);
    float hn = tanhf(acc);
    hs[cur ^ 1][j] = hn;                 // write other buffer (safe w/o barrier)
    hout[((long)b * S_ + t) * 128 + j] = hn;
    cur ^= 1;
    __syncthreads();
  }
}

// ---------------- K3: decay attention + build out_pu (fp32 out, bf16 A) ----------------
__global__ __launch_bounds__(128)
void attn_k(const float* __restrict__ ts, const float* __restrict__ loc,
            const float* __restrict__ hout, const int* __restrict__ auser,
            const float* __restrict__ userW, float* __restrict__ outpu,
            __hip_bfloat16* __restrict__ Abf) {
  int i = blockIdx.x, b = blockIdx.y, h = threadIdx.x;   // grid (200,64) x 128
  __shared__ float wl[128];
  const float OMEGA = 7.27220521664304e-05f;             // 2*pi/86400
  float ti = ts[b * S_ + i];
  float lx = loc[(b * S_ + i) * 2 + 0];
  float ly = loc[(b * S_ + i) * 2 + 1];
  float acc = 0.f, sw = 0.f;
  for (int jc = 0; jc <= i; jc += 128) {
    int j = jc + h;
    float wj = 0.f;
    if (j <= i) {
      float dt = fmaxf(ti - ts[b * S_ + j], 0.f);
      float a = (cosf(dt * OMEGA) + 1.f) * 0.5f * expf(-dt * 0.01f);
      float dx = lx - loc[(b * S_ + j) * 2 + 0];
      float dy = ly - loc[(b * S_ + j) * 2 + 1];
      float dn = sqrtf(dx * dx + dy * dy);
      wj = a * expf(-dn * 100.f) + 1e-10f;
    }
    __syncthreads();
    wl[h] = wj;
    __syncthreads();
    int lim = min(128, i - jc + 1);
    const float* hb = hout + ((long)b * S_ + jc) * 128 + h;
    for (int jj = 0; jj < lim; ++jj) {
      float wv = wl[jj];
      acc = fmaf(wv, hb[(long)jj * 128], acc);
      sw += wv;
    }
  }
  float ow = acc / fmaxf(sw, 1e-10f);
  long m = (long)b * S_ + i;
  float pu = userW[(long)auser[b] * 128 + h];
  outpu[m * 256 + h]       = ow;
  outpu[m * 256 + 128 + h] = pu;
  Abf[m * 256 + h]         = __float2bfloat16(ow);
  Abf[m * 256 + 128 + h]   = __float2bfloat16(pu);
}

// ---------------- K4/K5: FC GEMM (m97 structure) ----------------
// PASS 0: per-row partial sum of exp(logit) -> part[bn][row]
// PASS 1: y[row][col] = exp(logit) / rowsum[row]
template <int PASS>
__global__ __launch_bounds__(256)
void gemm_fc(const __hip_bfloat16* __restrict__ A,    // [12800][256]
             const __hip_bfloat16* __restrict__ Bw,   // [20096][256] (= fc_W^T-layout rows)
             const float* __restrict__ fcb,           // [20096], pad = -1e30
             const float* __restrict__ rowsum,        // [12800] (PASS 1)
             float* __restrict__ part,                 // [NBN][12800] (PASS 0)
             float* __restrict__ y) {                  // [12800][20000] (PASS 1)
  __shared__ __align__(16) __hip_bfloat16 As[128 * 32];
  __shared__ __align__(16) __hip_bfloat16 Bs[128 * 32];
  __shared__ float rsum2[2][128];

  const int tid  = threadIdx.x;
  const int lane = tid & 63;
  const int wid  = tid >> 6;
  const int wr = wid >> 1, wc = wid & 1;
  const int g = lane >> 4, lr = lane & 15;
  const int bn = blockIdx.x, bm = blockIdx.y;
  const long brow = (long)bm * 128, bcol = (long)bn * 128;

  f32x4 acc[4][4];
#pragma unroll
  for (int mi = 0; mi < 4; ++mi)
#pragma unroll
    for (int ni = 0; ni < 4; ++ni) acc[mi][ni] = (f32x4)(0.f);

  const char* Ab = (const char*)A + brow * 512;   // row stride 256*2B
  const char* Bb = (const char*)Bw + bcol * 512;
  char* AsB = (char*)As;
  char* BsB = (char*)Bs;
  const int c0 = tid, c1 = tid + 256;
  const int r0 = c0 >> 2, o0 = (c0 & 3) * 16;
  const int r1 = c1 >> 2, o1 = (c1 & 3) * 16;

  for (int kk = 0; kk < 8; ++kk) {
    __syncthreads();
    const int kb = kk * 64;                        // 32 bf16 = 64 bytes of K
    gll16(Ab + (long)r0 * 512 + kb + o0, AsB + c0 * 16);
    gll16(Ab + (long)r1 * 512 + kb + o1, AsB + c1 * 16);
    gll16(Bb + (long)r0 * 512 + kb + o0, BsB + c0 * 16);
    gll16(Bb + (long)r1 * 512 + kb + o1, BsB + c1 * 16);
    __syncthreads();
    bf16x8 af[4], bfr[4];
#pragma unroll
    for (int mi = 0; mi < 4; ++mi)
      af[mi] = *(const bf16x8*)(As + (wr * 64 + mi * 16 + lr) * 32 + g * 8);
#pragma unroll
    for (int ni = 0; ni < 4; ++ni)
      bfr[ni] = *(const bf16x8*)(Bs + (wc * 64 + ni * 16 + lr) * 32 + g * 8);
#pragma unroll
    for (int mi = 0; mi < 4; ++mi)
#pragma unroll
      for (int ni = 0; ni < 4; ++ni)
        acc[mi][ni] = __builtin_amdgcn_mfma_f32_16x16x32_bf16(af[mi], bfr[ni], acc[mi][ni], 0, 0, 0);
  }

  float fb[4];
#pragma unroll
  for (int ni = 0; ni < 4; ++ni) fb[ni] = fcb[bcol + wc * 64 + ni * 16 + lr];

  if (PASS == 0) {
#pragma unroll
    for (int mi = 0; mi < 4; ++mi) {
#pragma unroll
      for (int r = 0; r < 4; ++r) {
        float s = 0.f;
#pragma unroll
        for (int ni = 0; ni < 4; ++ni) s += __expf(acc[mi][ni][r] + fb[ni]);
#pragma unroll
        for (int off = 1; off < 16; off <<= 1) s += __shfl_xor(s, off);
        if (lr == 0) rsum2[wc][wr * 64 + mi * 16 + g * 4 + r] = s;
      }
    }
    __syncthreads();
    if (tid < 128)
      part[(long)bn * M_ + brow + tid] = rsum2[0][tid] + rsum2[1][tid];
  } else {
#pragma unroll
    for (int mi = 0; mi < 4; ++mi) {
#pragma unroll
      for (int r = 0; r < 4; ++r) {
        long row = brow + wr * 64 + mi * 16 + g * 4 + r;
        float inv = 1.0f / rowsum[row];
        long base = row * (long)V_;
#pragma unroll
        for (int ni = 0; ni < 4; ++ni) {
          int col = (int)bcol + wc * 64 + ni * 16 + lr;
          if (col < V_) y[base + col] = __expf(acc[mi][ni][r] + fb[ni]) * inv;
        }
      }
    }
  }
}

__global__ void reduce_rows(const float* __restrict__ part, float* __restrict__ rowsum) {
  int m = blockIdx.x * 256 + threadIdx.x;            // grid 50 x 256
  if (m < M_) {
    float s = 0.f;
    for (int bn = 0; bn < NBN; ++bn) s += part[(long)bn * M_ + m];
    rowsum[m] = fmaxf(s, 1e-30f);
  }
}

// ---------------- launcher ----------------
extern "C" void kernel_launch(void* const* d_in, const int* in_sizes, int n_in,
                              void* d_out, int out_size, void* d_ws, size_t ws_size,
                              hipStream_t stream) {
  const int*   poi   = (const int*)d_in[0];
  // d_in[1] = lengths (all == S, unused)
  const float* ts    = (const float*)d_in[2];
  const float* loc   = (const float*)d_in[3];
  const int*   auser = (const int*)d_in[4];
  const float* embW  = (const float*)d_in[5];
  const float* userW = (const float*)d_in[6];
  const float* w_ih  = (const float*)d_in[7];
  const float* w_hh  = (const float*)d_in[8];
  const float* b_ih  = (const float*)d_in[9];
  const float* b_hh  = (const float*)d_in[10];
  const float* fcW   = (const float*)d_in[11];
  const float* fcb   = (const float*)d_in[12];

  float* out = (float*)d_out;
  char*  ws  = (char*)d_ws;
  __hip_bfloat16* Abf    = (__hip_bfloat16*)(ws + WS_A);
  __hip_bfloat16* fcWb   = (__hip_bfloat16*)(ws + WS_FCW);
  float*          fcbp   = (float*)(ws + WS_FCB);
  float*          rowsum = (float*)(ws + WS_RSUM);
  float*          wt_ih  = (float*)(ws + WS_WTIH);

  float* xp    = out + XP_OFF;     // scratch inside y region (overwritten by pass 1)
  float* hout  = out + HOUT_OFF;
  float* part  = out + PART_OFF;
  float* outpu = out + OUTPU_OFF;  // real output 1

  prep_fcw<<<dim3(NPAD), dim3(256), 0, stream>>>(fcW, fcWb);
  prep_small<<<dim3(207), dim3(256), 0, stream>>>(w_ih, fcb, wt_ih, fcbp);
  xproj_k<<<dim3(M_), dim3(128), 0, stream>>>(poi, embW, wt_ih, b_ih, b_hh, xp);
  rnn_k<<<dim3(B_), dim3(128), 0, stream>>>(xp, w_hh, hout);
  attn_k<<<dim3(S_, B_), dim3(128), 0, stream>>>(ts, loc, hout, auser, userW, outpu, Abf);
  gemm_fc<0><<<dim3(NBN, NBM), dim3(256), 0, stream>>>(Abf, fcWb, fcbp, nullptr, part, nullptr);
  reduce_rows<<<dim3(50), dim3(256), 0, stream>>>(part, rowsum);
  gemm_fc<1><<<dim3(NBN, NBM), dim3(256), 0, stream>>>(Abf, fcWb, fcbp, rowsum, nullptr, out);
}